// Round 8
// baseline (389.988 us; speedup 1.0000x reference)
//
#include <hip/hip_runtime.h>
#include <stdint.h>

typedef unsigned short bfu;
typedef __attribute__((ext_vector_type(8))) short bf16x8;   // MFMA A/B frag
typedef __attribute__((ext_vector_type(4))) float f32x4;    // MFMA C/D frag

__device__ __forceinline__ bfu f2b(float f) {
  unsigned int i = __builtin_bit_cast(unsigned int, f);
  i += 0x7FFFu + ((i >> 16) & 1u);  // round-to-nearest-even
  return (bfu)(i >> 16);
}

// async global->LDS, 16B per lane: LDS dest = wave-uniform base + lane*16.
__device__ __forceinline__ void stage16(const bfu* g, bfu* l) {
  __builtin_amdgcn_global_load_lds(
      (const __attribute__((address_space(1))) void*)g,
      (__attribute__((address_space(3))) void*)l, 16, 0, 0);
}

// C[M,N] = A[M,K] @ B[N,K]^T. 64x128 tile, BK=64, global_load_lds staging.
// MODE 0: atomicAdd f32 (split-K via blockIdx.z when zIsK)
// MODE 1: store bf16 via LDS repack (swizzled, 16B/lane stores)
template <int MODE>
__global__ __launch_bounds__(256) void gemm64(
    const bfu* __restrict__ A, const bfu* __restrict__ B, void* __restrict__ Cv,
    int lda, int ldb, int ldc,
    long long sA, long long sB, long long sC,
    int Klen, int zIsK) {
  __shared__ __align__(16) bfu S[12288];  // At 64x64 (8KB) + Bt 128x64 (16KB)
  bfu* At = S;
  bfu* Bt = S + 4096;
  const int tid = threadIdx.x;
  const int lane = tid & 63;
  const int wid = tid >> 6;
  const int l15 = lane & 15, l4 = lane >> 4;
  const int wm = wid >> 1, wn = wid & 1;

  int k0 = 0;
  long long cOff = 0;
  if (zIsK) {
    k0 = blockIdx.z * Klen;
  } else {
    A += (long long)blockIdx.z * sA;
    B += (long long)blockIdx.z * sB;
    cOff = (long long)blockIdx.z * sC;
  }
  const int m0 = blockIdx.y * 64;
  const int n0 = blockIdx.x * 128;
  const bfu* Ag = A + (long long)m0 * lda + k0;
  const bfu* Bg = B + (long long)n0 * ldb + k0;

  f32x4 acc[2][4];
  const f32x4 zero = {0.f, 0.f, 0.f, 0.f};
#pragma unroll
  for (int r = 0; r < 2; ++r)
#pragma unroll
    for (int c = 0; c < 4; ++c) acc[r][c] = zero;

  const int lrow = lane >> 3;
  const int lcol = (lane & 7) * 8;

  const int nIter = Klen >> 6;
  for (int kt = 0; kt < nIter; ++kt) {
    const bfu* Ak = Ag + kt * 64;
    const bfu* Bk = Bg + kt * 64;
#pragma unroll
    for (int j = 0; j < 2; ++j) {
      const int row = (wid * 2 + j) * 8 + lrow;
      stage16(Ak + (long long)row * lda + lcol, At + row * 64 + lcol);
    }
#pragma unroll
    for (int j = 0; j < 4; ++j) {
      const int row = (wid * 4 + j) * 8 + lrow;
      stage16(Bk + (long long)row * ldb + lcol, Bt + row * 64 + lcol);
    }
    __syncthreads();
#pragma unroll
    for (int kk = 0; kk < 2; ++kk) {
      const int ko = kk * 32 + l4 * 8;
      bf16x8 af[2], bfr[4];
#pragma unroll
      for (int r = 0; r < 2; ++r)
        af[r] = *(const bf16x8*)(At + (wm * 32 + r * 16 + l15) * 64 + ko);
#pragma unroll
      for (int c = 0; c < 4; ++c)
        bfr[c] = *(const bf16x8*)(Bt + (wn * 64 + c * 16 + l15) * 64 + ko);
#pragma unroll
      for (int r = 0; r < 2; ++r)
#pragma unroll
        for (int c = 0; c < 4; ++c)
          acc[r][c] = __builtin_amdgcn_mfma_f32_16x16x32_bf16(af[r], bfr[c], acc[r][c], 0, 0, 0);
    }
    __syncthreads();
  }

  if (MODE == 0) {
    float* Cf = (float*)Cv;
#pragma unroll
    for (int r = 0; r < 2; ++r) {
#pragma unroll
      for (int c = 0; c < 4; ++c) {
        const int gr = m0 + wm * 32 + r * 16 + (l4 << 2);
        const int gc = n0 + wn * 64 + c * 16 + l15;
#pragma unroll
        for (int v = 0; v < 4; ++v)
          atomicAdd(Cf + cOff + (long long)(gr + v) * ldc + gc, acc[r][c][v]);
      }
    }
  } else {
#pragma unroll
    for (int r = 0; r < 2; ++r) {
#pragma unroll
      for (int c = 0; c < 4; ++c) {
        const int col = wn * 64 + c * 16 + l15;
#pragma unroll
        for (int v = 0; v < 4; ++v) {
          const int row = wm * 32 + r * 16 + (l4 << 2) + v;
          S[row * 128 + (col ^ (((row >> 2) & 3) << 4))] = f2b(acc[r][c][v]);
        }
      }
    }
    __syncthreads();
    bfu* Cb = (bfu*)Cv;
#pragma unroll
    for (int i = 0; i < 4; ++i) {
      const int j = i * 256 + tid;
      const int row = j >> 4;
      const int colbase = (j & 15) * 8;
      const int sc = colbase ^ (((row >> 2) & 3) << 4);
      uint4 val = *(const uint4*)(S + row * 128 + sc);
      *(uint4*)(Cb + cOff + (long long)(m0 + row) * ldc + n0 + colbase) = val;
    }
  }
}

// ---------- fused logits + softmax: P[s0..s0+32][h*512..+512] -> Ecat ----------
// Block = 32 s-rows x one full head (512 cols). K=512, BK=32.
// acc[2][8]: wave w owns cols w*128..+128 (8 col-tiles), rows 32 (2 row-tiles).
__global__ __launch_bounds__(256) void logits_fused(
    const bfu* __restrict__ Xb,   // [8192][512]
    const bfu* __restrict__ Mb,   // [8][512][512]
    const float* __restrict__ cb, // [8][512]
    bfu* __restrict__ Ecat) {     // [8192][4096]
  __shared__ __align__(16) bfu Bs[16384];  // 32 KB: B-tile staging, then P tile
  __shared__ float redA[4][32];
  __shared__ float redB[4][32];
  const int tid = threadIdx.x;
  const int lane = tid & 63;
  const int w = tid >> 6;
  const int l15 = lane & 15, l4 = lane >> 4;
  const int s0 = blockIdx.x * 32;
  const int h = blockIdx.y;
  const float scale = 0.044194173824159216f;  // 1/sqrt(512)

  const bfu* Bg = Mb + h * 262144;  // [512 a][512 x]
  f32x4 acc[2][8];
  const f32x4 zero = {0.f, 0.f, 0.f, 0.f};
#pragma unroll
  for (int rg = 0; rg < 2; ++rg)
#pragma unroll
    for (int cf = 0; cf < 8; ++cf) acc[rg][cf] = zero;

  for (int kt = 0; kt < 16; ++kt) {
    const int k0 = kt * 32;
    // stage B rows [0,512) x K-cols [k0,k0+32): chunk c: row=c>>2, kc=c&3
#pragma unroll
    for (int j = 0; j < 8; ++j) {
      const int c = j * 256 + tid;
      stage16(Bg + (c >> 2) * 512 + k0 + (c & 3) * 8, Bs + c * 8);
    }
    __syncthreads();
    bf16x8 af[2];
#pragma unroll
    for (int rg = 0; rg < 2; ++rg)
      af[rg] = *(const bf16x8*)(Xb + (long long)(s0 + rg * 16 + l15) * 512 + k0 + l4 * 8);
#pragma unroll
    for (int cf = 0; cf < 8; ++cf) {
      const int a = w * 128 + cf * 16 + l15;
      bf16x8 bfr = *(const bf16x8*)(Bs + a * 32 + l4 * 8);
#pragma unroll
      for (int rg = 0; rg < 2; ++rg)
        acc[rg][cf] = __builtin_amdgcn_mfma_f32_16x16x32_bf16(af[rg], bfr, acc[rg][cf], 0, 0, 0);
    }
    __syncthreads();
  }

  // + cb, scale
  float cbl[8];
#pragma unroll
  for (int cf = 0; cf < 8; ++cf) cbl[cf] = cb[h * 512 + w * 128 + cf * 16 + l15];
#pragma unroll
  for (int rg = 0; rg < 2; ++rg)
#pragma unroll
    for (int cf = 0; cf < 8; ++cf)
#pragma unroll
      for (int v = 0; v < 4; ++v)
        acc[rg][cf][v] = (acc[rg][cf][v] + cbl[cf]) * scale;

  // row max: in-lane over cf, cross-l15 shfl, cross-wave via LDS (R6-verified)
  float pm[2][4];
#pragma unroll
  for (int rg = 0; rg < 2; ++rg)
#pragma unroll
    for (int v = 0; v < 4; ++v) pm[rg][v] = -3.0e38f;
#pragma unroll
  for (int rg = 0; rg < 2; ++rg)
#pragma unroll
    for (int cf = 0; cf < 8; ++cf)
#pragma unroll
      for (int v = 0; v < 4; ++v) pm[rg][v] = fmaxf(pm[rg][v], acc[rg][cf][v]);
#pragma unroll
  for (int m = 1; m < 16; m <<= 1)
#pragma unroll
    for (int rg = 0; rg < 2; ++rg)
#pragma unroll
      for (int v = 0; v < 4; ++v)
        pm[rg][v] = fmaxf(pm[rg][v], __shfl_xor(pm[rg][v], m, 64));
  if (l15 == 0)
#pragma unroll
    for (int rg = 0; rg < 2; ++rg)
#pragma unroll
      for (int v = 0; v < 4; ++v) redA[w][rg * 16 + l4 * 4 + v] = pm[rg][v];
  __syncthreads();
  float rmax[2][4];
#pragma unroll
  for (int rg = 0; rg < 2; ++rg)
#pragma unroll
    for (int v = 0; v < 4; ++v) {
      const int row = rg * 16 + l4 * 4 + v;
      rmax[rg][v] = fmaxf(fmaxf(redA[0][row], redA[1][row]),
                          fmaxf(redA[2][row], redA[3][row]));
    }
  float ps[2][4];
#pragma unroll
  for (int rg = 0; rg < 2; ++rg)
#pragma unroll
    for (int v = 0; v < 4; ++v) ps[rg][v] = 0.f;
#pragma unroll
  for (int rg = 0; rg < 2; ++rg)
#pragma unroll
    for (int cf = 0; cf < 8; ++cf)
#pragma unroll
      for (int v = 0; v < 4; ++v) {
        const float e = __expf(acc[rg][cf][v] - rmax[rg][v]);
        acc[rg][cf][v] = e;
        ps[rg][v] += e;
      }
#pragma unroll
  for (int m = 1; m < 16; m <<= 1)
#pragma unroll
    for (int rg = 0; rg < 2; ++rg)
#pragma unroll
      for (int v = 0; v < 4; ++v) ps[rg][v] += __shfl_xor(ps[rg][v], m, 64);
  if (l15 == 0)
#pragma unroll
    for (int rg = 0; rg < 2; ++rg)
#pragma unroll
      for (int v = 0; v < 4; ++v) redB[w][rg * 16 + l4 * 4 + v] = ps[rg][v];
  __syncthreads();
  float rinv[2][4];
#pragma unroll
  for (int rg = 0; rg < 2; ++rg)
#pragma unroll
    for (int v = 0; v < 4; ++v) {
      const int row = rg * 16 + l4 * 4 + v;
      rinv[rg][v] = 1.0f / (redB[0][row] + redB[1][row] + redB[2][row] + redB[3][row]);
    }

  // write P into Bs [32][512], XOR-swizzled by (row>>2)&3 on 16-col groups
#pragma unroll
  for (int rg = 0; rg < 2; ++rg)
#pragma unroll
    for (int cf = 0; cf < 8; ++cf) {
      const int colb = w * 128 + cf * 16 + l15;
#pragma unroll
      for (int v = 0; v < 4; ++v) {
        const int row = rg * 16 + l4 * 4 + v;
        Bs[row * 512 + (colb ^ (((row >> 2) & 3) << 4))] = f2b(acc[rg][cf][v] * rinv[rg][v]);
      }
    }
  __syncthreads();
  // coalesced store: 2048 uint4 chunks; row=c>>6, chunk=c&63 (8 cols each)
#pragma unroll
  for (int i = 0; i < 8; ++i) {
    const int c = i * 256 + tid;
    const int row = c >> 6;
    const int chunk = c & 63;
    const int schunk = chunk ^ (((row >> 2) & 3) << 1);
    uint4 val = *(const uint4*)(Bs + row * 512 + schunk * 8);
    *(uint4*)(Ecat + (long long)(s0 + row) * 4096 + h * 512 + chunk * 8) = val;
  }
}

// ---------------- helpers ----------------
__global__ void transpose_k(const float* __restrict__ in, bfu* __restrict__ out,
                            int R, int C) {
  __shared__ bfu t[32][33];
  const long long boff = (long long)blockIdx.z * R * C;
  const int c0 = blockIdx.x * 32, r0 = blockIdx.y * 32;
  const int tx = threadIdx.x, ty = threadIdx.y;
  for (int i = ty; i < 32; i += 8)
    t[i][tx] = f2b(in[boff + (long long)(r0 + i) * C + (c0 + tx)]);
  __syncthreads();
  for (int i = ty; i < 32; i += 8)
    out[boff + (long long)(c0 + i) * R + (r0 + tx)] = t[tx][i];
}

// one dispatch converting X, enc0, enc1, Wc to bf16 (float4-granular)
__global__ __launch_bounds__(256) void conv_all(
    const float* __restrict__ X, const float* __restrict__ e0,
    const float* __restrict__ e1, const float* __restrict__ Wc,
    bfu* __restrict__ Xb, bfu* __restrict__ e0b,
    bfu* __restrict__ e1b, bfu* __restrict__ Wcb) {
  int i = blockIdx.x * 256 + threadIdx.x;  // 0 .. 3670016
  const float* s; bfu* d; int off;
  if (i < 1048576)      { s = X;  d = Xb;  off = i; }
  else if (i < 2097152) { s = e0; d = e0b; off = i - 1048576; }
  else if (i < 3145728) { s = e1; d = e1b; off = i - 2097152; }
  else                  { s = Wc; d = Wcb; off = i - 3145728; }
  float4 f = ((const float4*)s)[off];
  ushort4 o;
  o.x = f2b(f.x); o.y = f2b(f.y); o.z = f2b(f.z); o.w = f2b(f.w);
  ((ushort4*)d)[off] = o;
}

__global__ __launch_bounds__(256) void zero_k(float* __restrict__ p) {
  p[blockIdx.x * 256 + threadIdx.x] = 0.f;
}

__global__ __launch_bounds__(256) void zero_out_k(float* __restrict__ p, int n) {
  int i = blockIdx.x * 256 + threadIdx.x;
  if (i < n) p[i] = 0.f;
}

// d_out[s][c] = bc[c]  (split-K final GEMM accumulates atomically on top)
__global__ __launch_bounds__(256) void init_out(float* __restrict__ out,
                                                const float* __restrict__ bc) {
  int i = blockIdx.x * 256 + threadIdx.x;
  out[i] = bc[i & 511];
}

__global__ __launch_bounds__(256) void cast_kv(const float* __restrict__ K32,
                                               const float* __restrict__ V32,
                                               bfu* __restrict__ Kb, bfu* __restrict__ VTb) {
  int idx = blockIdx.x * 256 + threadIdx.x;
  int a = idx >> 9, b = idx & 511;
  Kb[idx] = f2b(K32[idx]);
  VTb[idx] = f2b(V32[b * 512 + a]);
}

__global__ __launch_bounds__(256) void cvec_k(const float* __restrict__ K32,
                                              const float* __restrict__ bq,
                                              float* __restrict__ cb) {
  const int lane = threadIdx.x & 63;
  const int w = blockIdx.x * 4 + (threadIdx.x >> 6);
  const int h = w >> 9, a = w & 511;
  float s = 0.f;
#pragma unroll
  for (int i = 0; i < 8; ++i) {
    int q = i * 64 + lane;
    s += K32[a * 512 + q] * bq[h * 512 + q];
  }
#pragma unroll
  for (int off = 32; off; off >>= 1) s += __shfl_xor(s, off, 64);
  if (lane == 0) cb[w] = s;
}

extern "C" void kernel_launch(void* const* d_in, const int* in_sizes, int n_in,
                              void* d_out, int out_size, void* d_ws, size_t ws_size,
                              hipStream_t stream) {
  (void)in_sizes; (void)n_in;
  const float* X    = (const float*)d_in[0];  // [8192,512]
  const float* enc0 = (const float*)d_in[1];  // [512,8192]
  const float* enc1 = (const float*)d_in[2];  // [512,8192]
  const float* Wq   = (const float*)d_in[3];  // [8,512,512]
  const float* bq   = (const float*)d_in[4];  // [8,512]
  const float* Wc   = (const float*)d_in[5];  // [512,4096]
  const float* bc   = (const float*)d_in[6];  // [512]
  float* out = (float*)d_out;                 // [8192,512] f32

  const size_t NEED = 83902464;  // 80.02 MB
  if (ws_size < NEED) {
    zero_out_k<<<dim3((out_size + 255) / 256), 256, 0, stream>>>(out, out_size);
    return;
  }
  char* w = (char*)d_ws;
  bfu*   Ecat  = (bfu*)(w + 0);           // [8192][4096] 64 MB
  bfu*   XTb   = (bfu*)(w + 0);           // [512][8192]   8 MB (transient)
  bfu*   enc0b = (bfu*)(w + 8388608);     // [512][8192]   8 MB (transient)
  bfu*   enc1b = (bfu*)(w + 16777216);    // [512][8192]   8 MB (transient)
  bfu*   WqTb  = (bfu*)(w + 25165824);    // [8][512][512] 4 MB (transient)
  bfu*   Wcb   = (bfu*)(w + 29360128);    // [512][4096]   4 MB (transient)
  float* K32   = (float*)(w + 33554432);  // [512][512]    1 MB (transient)
  float* V32   = (float*)(w + 34603008);  // [512][512]    1 MB (transient)
  bfu*   Kb    = (bfu*)(w + 35651584);    // [512][512]  0.5 MB (transient)
  bfu*   VTb   = (bfu*)(w + 36175872);    // [512][512]  0.5 MB (transient)
  bfu*   Xb    = (bfu*)(w + 67108864);    // [8192][512]   8 MB
  bfu*   Mb    = (bfu*)(w + 75497472);    // [8][512][512] 4 MB
  bfu*   Ncat  = (bfu*)(w + 79691776);    // [512][4096]   4 MB
  float* cb    = (float*)(w + 83886080);  // [8][512]     16 KB

  conv_all<<<dim3(14336), 256, 0, stream>>>(X, enc0, enc1, Wc, Xb, enc0b, enc1b, Wcb);

  dim3 tb(32, 8, 1);
  transpose_k<<<dim3(16, 256, 1), tb, 0, stream>>>(X, XTb, 8192, 512);
  transpose_k<<<dim3(16, 16, 8), tb, 0, stream>>>(Wq, WqTb, 512, 512);

  zero_k<<<dim3(2048), 256, 0, stream>>>(K32);        // K32+V32 contiguous
  init_out<<<dim3(16384), 256, 0, stream>>>(out, bc); // bias pre-fill

  // K = enc0 @ X, V = enc1 @ X  (split-K over 16 chunks of 512; 512 blocks)
  gemm64<0><<<dim3(4, 8, 16), 256, 0, stream>>>(enc0b, XTb, K32,
      8192, 8192, 512, 0, 0, 0, 512, 1);
  gemm64<0><<<dim3(4, 8, 16), 256, 0, stream>>>(enc1b, XTb, V32,
      8192, 8192, 512, 0, 0, 0, 512, 1);
  cast_kv<<<dim3(1024), 256, 0, stream>>>(K32, V32, Kb, VTb);
  cvec_k<<<dim3(1024), 256, 0, stream>>>(K32, bq, cb);

  // M_h = K @ Wq_h
  gemm64<1><<<dim3(4, 8, 8), 256, 0, stream>>>(Kb, WqTb, Mb,
      512, 512, 512, 0, 262144, 262144, 512, 0);
  // N_h = Wc_h @ V -> Ncat[o][h*512+a]
  gemm64<1><<<dim3(4, 8, 8), 256, 0, stream>>>(Wcb, VTb, Ncat,
      4096, 512, 4096, 512, 0, 512, 512, 0);

  // fused logits+softmax -> Ecat (2048 blocks)
  logits_fused<<<dim3(256, 8), 256, 0, stream>>>(Xb, Mb, cb, Ecat);

  // out += Ecat @ Ncat^T  (split-K=2 -> 1024 blocks = 4/CU, atomic f32)
  gemm64<0><<<dim3(4, 128, 2), 256, 0, stream>>>(Ecat, Ncat, out,
      4096, 4096, 512, 0, 0, 0, 2048, 1);
}